// Round 10
// baseline (530.780 us; speedup 1.0000x reference)
//
#include <hip/hip_runtime.h>
#include <hip/hip_bf16.h>

typedef __attribute__((ext_vector_type(8))) short s8v;
typedef __attribute__((ext_vector_type(4))) float f4v;

#define NNODES 100000
#define NEDGES 1600000
#define NFEAT 512
#define NHID 128
#define NCLS 64
#define NB1 391   // ceil(NNODES/256)

static __device__ __forceinline__ short f2bf(float f) {
  __hip_bfloat16 h = __float2bfloat16(f);
  return __builtin_bit_cast(short, h);
}
static __device__ __forceinline__ float bflo(unsigned int u) {
  return __builtin_bit_cast(float, u << 16);
}
static __device__ __forceinline__ float bfhi(unsigned int u) {
  return __builtin_bit_cast(float, u & 0xFFFF0000u);
}
static __device__ __forceinline__ unsigned int pk(float lo, float hi) {
  return (unsigned int)(unsigned short)f2bf(lo) |
         ((unsigned int)(unsigned short)f2bf(hi) << 16);
}
static __device__ __forceinline__ void glds16(const void* g, void* l) {
  __builtin_amdgcn_global_load_lds(
      (const __attribute__((address_space(1))) unsigned int*)g,
      (__attribute__((address_space(3))) unsigned int*)l, 16, 0, 0);
}

// per-block edge-dtype detection: int64 => odd 32-bit words of first 1024 pairs all zero
static __device__ __forceinline__ bool detect32(const int* __restrict__ ei, int* sm) {
  if (threadIdx.x == 0) *sm = 0;
  __syncthreads();
  int i = threadIdx.x & 255;
  int acc = ei[2 * i + 1] | ei[2 * (i + 256) + 1] |
            ei[2 * (i + 512) + 1] | ei[2 * (i + 768) + 1];
  if (acc != 0) atomicOr(sm, 1);
  __syncthreads();
  return *sm != 0;
}

__global__ __launch_bounds__(256) void hist_k(const int* __restrict__ ei,
                                              int* __restrict__ cnt) {
  __shared__ int sm;
  bool is32 = detect32(ei, &sm);
  int stride = gridDim.x * blockDim.x;
  for (int e = blockIdx.x * blockDim.x + threadIdx.x; e < NEDGES; e += stride) {
    int d = is32 ? ei[NEDGES + e] : ei[2 * NEDGES + 2 * e];
    atomicAdd(&cnt[d], 1);
  }
}

// ---- hierarchical exclusive scan of cnt -> rs (+ rs2 cursor copy, dinv) ----
__global__ __launch_bounds__(256) void scan1_k(const int* __restrict__ cnt,
                                               int* __restrict__ rs,
                                               int* __restrict__ bsum) {
  __shared__ int sm[256];
  int t = threadIdx.x;
  int i = blockIdx.x * 256 + t;
  int v = (i < NNODES) ? cnt[i] : 0;
  sm[t] = v;
  __syncthreads();
  for (int off = 1; off < 256; off <<= 1) {
    int val = (t >= off) ? sm[t - off] : 0;
    __syncthreads();
    sm[t] += val;
    __syncthreads();
  }
  if (i < NNODES) rs[i] = sm[t] - v;
  if (t == 255) bsum[blockIdx.x] = sm[255];
}

__global__ __launch_bounds__(512) void scan2_k(int* __restrict__ bsum, int* __restrict__ rs) {
  __shared__ int sm[512];
  int t = threadIdx.x;
  int v = (t < NB1) ? bsum[t] : 0;
  sm[t] = v;
  __syncthreads();
  for (int off = 1; off < 512; off <<= 1) {
    int val = (t >= off) ? sm[t - off] : 0;
    __syncthreads();
    sm[t] += val;
    __syncthreads();
  }
  if (t < NB1) bsum[t] = sm[t] - v;
  if (t == 511) rs[NNODES] = sm[511];
}

__global__ __launch_bounds__(256) void scan3_k(const int* __restrict__ cnt,
                                               const int* __restrict__ bsum,
                                               int* __restrict__ rs,
                                               int* __restrict__ rs2,
                                               float* __restrict__ dinv) {
  int i = blockIdx.x * 256 + threadIdx.x;
  if (i < NNODES) {
    int v = rs[i] + bsum[blockIdx.x];
    rs[i] = v;
    rs2[i] = v;
    dinv[i] = rsqrtf((float)(cnt[i] + 1));
  }
}

__global__ __launch_bounds__(256) void scatter_k(const int* __restrict__ ei,
                                                 int* __restrict__ rs2,
                                                 int* __restrict__ csrc) {
  __shared__ int sm;
  bool is32 = detect32(ei, &sm);
  int stride = gridDim.x * blockDim.x;
  for (int e = blockIdx.x * blockDim.x + threadIdx.x; e < NEDGES; e += stride) {
    int s, d;
    if (is32) { s = ei[e];     d = ei[NEDGES + e]; }
    else      { s = ei[2 * e]; d = ei[2 * NEDGES + 2 * e]; }
    int pos = atomicAdd(&rs2[d], 1);
    csrc[pos] = s;
  }
}

// ---- weight transpose+convert (merged) ----
__global__ __launch_bounds__(256) void wt_k(const float* __restrict__ W1, short* __restrict__ W1t,
                                            const float* __restrict__ W2, short* __restrict__ W2t) {
  int i = blockIdx.x * 256 + threadIdx.x;
  if (i < NFEAT * NHID) {
    int k = i >> 7, c = i & 127;
    W1t[(size_t)c * NFEAT + k] = f2bf(W1[i]);
  } else {
    int j = i - NFEAT * NHID;
    if (j < NHID * NCLS) {
      int k = j >> 6, c = j & 63;
      W2t[(size_t)c * NHID + k] = f2bf(W2[j]);
    }
  }
}

// ---- fused MLP: BM=128, BK=64, 512 threads (8 waves), dbuf LDS A+B ----
__global__ __launch_bounds__(512, 4) void mlp3_k(const float* __restrict__ x,
                                                 const short* __restrict__ W1t,
                                                 const float* __restrict__ b1,
                                                 const short* __restrict__ W2t,
                                                 const float* __restrict__ b2,
                                                 const float* __restrict__ dinv,
                                                 unsigned short* __restrict__ x0,
                                                 unsigned short* __restrict__ g0) {
  __shared__ __align__(16) short As[2][8192]; // 2 x 128 rows x 64 k bf16
  __shared__ __align__(16) short Bs[2][8192]; // 2 x 128 col x 64 k bf16
  int tid = threadIdx.x, lane = tid & 63, wave = tid >> 6;
  int r = lane & 15, q = lane >> 4;
  int G = tid >> 4, li = tid & 15;        // A-staging: 32 row-groups x 16
  int row0 = blockIdx.x * 128;
  int wr = (wave >> 1) * 32, wc = (wave & 1) * 64;
  char* AsB = (char*)As;
  char* BsB = (char*)Bs;

  auto loadA = [&](float4* av, int kk) {
#pragma unroll
    for (int rd = 0; rd < 4; ++rd) {
      int row = rd * 32 + G;
      int grow = row0 + row; if (grow >= NNODES) grow = NNODES - 1;
      av[rd] = *reinterpret_cast<const float4*>(x + (size_t)grow * NFEAT + kk + li * 4);
    }
  };
  auto writeA = [&](const float4* av, int buf) {
#pragma unroll
    for (int rd = 0; rd < 4; ++rd) {
      int row = rd * 32 + G;
      uint2 u;
      u.x = pk(av[rd].x, av[rd].y);
      u.y = pk(av[rd].z, av[rd].w);
      *(uint2*)(AsB + buf * 16384 + row * 128 + (((li >> 1) ^ (row & 7)) << 4) + (li & 1) * 8) = u;
    }
  };
  auto stageB = [&](int buf, int kk) {
#pragma unroll
    for (int i2 = 0; i2 < 2; ++i2) {
      int i = wave * 2 + i2;
      int col = i * 8 + (lane >> 3);
      int srcg = (lane & 7) ^ (col & 7);
      glds16(W1t + (size_t)col * NFEAT + kk + srcg * 8, BsB + buf * 16384 + i * 1024);
    }
  };

  f4v acc[2][4];
#pragma unroll
  for (int a = 0; a < 2; ++a)
#pragma unroll
    for (int b = 0; b < 4; ++b) acc[a][b] = (f4v){0.f, 0.f, 0.f, 0.f};

  {
    float4 av[4];
    loadA(av, 0);
    stageB(0, 0);
    writeA(av, 0);
  }
  __syncthreads();

  int cur = 0;
  for (int c = 0; c < 8; ++c) {
    float4 av[4];
    if (c < 7) {               // issue next-tile loads early (T14)
      loadA(av, (c + 1) * 64);
      stageB(cur ^ 1, (c + 1) * 64);
    }
#pragma unroll
    for (int kc = 0; kc < 2; ++kc) {
      s8v af[2], bfr[4];
#pragma unroll
      for (int rt = 0; rt < 2; ++rt) {
        int arow = wr + rt * 16 + r;
        af[rt] = *(const s8v*)(AsB + cur * 16384 + arow * 128 +
                               (((kc * 4 + q) ^ (arow & 7)) << 4));
      }
#pragma unroll
      for (int ct = 0; ct < 4; ++ct) {
        int bcol = wc + ct * 16 + r;
        bfr[ct] = *(const s8v*)(BsB + cur * 16384 + bcol * 128 +
                                (((kc * 4 + q) ^ (bcol & 7)) << 4));
      }
#pragma unroll
      for (int rt = 0; rt < 2; ++rt)
#pragma unroll
        for (int ct = 0; ct < 4; ++ct)
          acc[rt][ct] = __builtin_amdgcn_mfma_f32_16x16x32_bf16(af[rt], bfr[ct], acc[rt][ct], 0, 0, 0);
    }
    if (c < 7) writeA(av, cur ^ 1);  // write-late
    __syncthreads();
    cur ^= 1;
  }

  // ---- h1 tile (relu, bf16) -> LDS (256B swizzled rows over As) ----
  {
    float bias1[4];
#pragma unroll
    for (int ct = 0; ct < 4; ++ct) bias1[ct] = b1[wc + ct * 16 + r];
#pragma unroll
    for (int rt = 0; rt < 2; ++rt)
#pragma unroll
      for (int ct = 0; ct < 4; ++ct) {
        int col = wc + ct * 16 + r;
#pragma unroll
        for (int j = 0; j < 4; ++j) {
          int row = wr + rt * 16 + q * 4 + j;
          float v = acc[rt][ct][j] + bias1[ct];
          v = v > 0.f ? v : 0.f;
          *(short*)(AsB + row * 256 + (((col >> 3) ^ (row & 15)) << 4) + (col & 7) * 2) = f2bf(v);
        }
      }
  }
  __syncthreads();

  // ---- gemm2: h1[128x128] @ W2t; wave: 32 rows x 32 cols ----
  int wc2 = (wave & 1) * 32;
  f4v acc2[2][2];
#pragma unroll
  for (int a = 0; a < 2; ++a)
#pragma unroll
    for (int b = 0; b < 2; ++b) acc2[a][b] = (f4v){0.f, 0.f, 0.f, 0.f};
#pragma unroll
  for (int kc = 0; kc < 4; ++kc) {
    s8v a2[2], b2f[2];
#pragma unroll
    for (int rt = 0; rt < 2; ++rt) {
      int row = wr + rt * 16 + r;
      a2[rt] = *(const s8v*)(AsB + row * 256 + (((kc * 4 + q) ^ (row & 15)) << 4));
    }
#pragma unroll
    for (int ct = 0; ct < 2; ++ct) {
      int col2 = wc2 + ct * 16 + r;
      b2f[ct] = *(const s8v*)(W2t + (size_t)col2 * NHID + kc * 32 + q * 8);
    }
#pragma unroll
    for (int rt = 0; rt < 2; ++rt)
#pragma unroll
      for (int ct = 0; ct < 2; ++ct)
        acc2[rt][ct] = __builtin_amdgcn_mfma_f32_16x16x32_bf16(a2[rt], b2f[ct], acc2[rt][ct], 0, 0, 0);
  }

  // ---- epilogue: pack x0/g0 into Bs (swizzled 128B rows), coalesced stores ----
  {
    float bias2[2];
#pragma unroll
    for (int ct = 0; ct < 2; ++ct) bias2[ct] = b2[wc2 + ct * 16 + r];
#pragma unroll
    for (int rt = 0; rt < 2; ++rt)
#pragma unroll
      for (int j = 0; j < 4; ++j) {
        int row = wr + rt * 16 + q * 4 + j;
        int grow = row0 + row;
        float dv = dinv[grow < NNODES ? grow : NNODES - 1];
#pragma unroll
        for (int ct = 0; ct < 2; ++ct) {
          float hh = acc2[rt][ct][j] + bias2[ct];
          int col = wc2 + ct * 16 + r;
          int byte = row * 128 + (((col >> 3) ^ (row & 7)) << 4) + (col & 7) * 2;
          *(short*)(BsB + byte) = f2bf(hh);
          *(short*)(BsB + 16384 + byte) = f2bf(dv * hh);
        }
      }
  }
  __syncthreads();
#pragma unroll
  for (int rd = 0; rd < 4; ++rd) {
    int row = rd * 32 + G;
    int grow = row0 + row;
    if (grow < NNODES) {
      int byte = row * 128 + (((li >> 1) ^ (row & 7)) << 4) + (li & 1) * 8;
      uint2 vx = *(const uint2*)(BsB + byte);
      uint2 vg = *(const uint2*)(BsB + 16384 + byte);
      *(uint2*)(x0 + (size_t)grow * NCLS + li * 4) = vx;
      *(uint2*)(g0 + (size_t)grow * NCLS + li * 4) = vg;
    }
  }
}

// ---- propagation: 8 nodes/wave, 8 lanes/node, uint4 gathers, pipelined csrc ----
__global__ __launch_bounds__(256) void prop_k(const unsigned short* __restrict__ gin,
                                              const unsigned short* __restrict__ x0,
                                              const float* __restrict__ dinv,
                                              const int* __restrict__ rs,
                                              const int* __restrict__ csrc,
                                              unsigned short* __restrict__ gout,
                                              float* __restrict__ out,
                                              int last) {
  int tid = threadIdx.x;
  int lane = tid & 63;
  int r = lane & 7;        // 8 lanes per node
  int gbase = lane & 56;
  int node = blockIdx.x * 32 + (tid >> 6) * 8 + (lane >> 3); // 3125*32 == NNODES
  int b = rs[node];
  int deg = rs[node + 1] - b;

  // hoisted loop-invariant loads (issue early)
  uint4 sv = ((const uint4*)(gin + (size_t)node * NCLS))[r];
  uint4 xv = ((const uint4*)(x0 + (size_t)node * NCLS))[r];
  float dvn = dinv[node];

  float a0 = bflo(sv.x), a1 = bfhi(sv.x), a2 = bflo(sv.y), a3 = bfhi(sv.y);
  float a4 = bflo(sv.z), a5 = bfhi(sv.z), a6 = bflo(sv.w), a7 = bfhi(sv.w);

  int m = deg;  // wave-uniform max
  m = max(m, __shfl_xor(m, 8));
  m = max(m, __shfl_xor(m, 16));
  m = max(m, __shfl_xor(m, 32));

  // software-pipelined index chunks: prefetch chunk k+1 while gathering chunk k
  int idx = NNODES;                       // null row (zeroed)
  if (r < deg) idx = csrc[b + r];
  for (int basek = 0; basek < m; basek += 8) {
    int nidx = NNODES;
    if (basek + 8 + r < deg) nidx = csrc[b + basek + 8 + r];
#pragma unroll
    for (int j = 0; j < 8; ++j) {
      int sj = __shfl(idx, gbase + j);
      uint4 v = ((const uint4*)(gin + (size_t)sj * NCLS))[r];
      a0 += bflo(v.x); a1 += bfhi(v.x); a2 += bflo(v.y); a3 += bfhi(v.y);
      a4 += bflo(v.z); a5 += bfhi(v.z); a6 += bflo(v.w); a7 += bfhi(v.w);
    }
    idx = nidx;
  }

  float h0 = 0.9f * (dvn * a0) + 0.1f * bflo(xv.x);
  float h1 = 0.9f * (dvn * a1) + 0.1f * bfhi(xv.x);
  float h2 = 0.9f * (dvn * a2) + 0.1f * bflo(xv.y);
  float h3 = 0.9f * (dvn * a3) + 0.1f * bfhi(xv.y);
  float h4 = 0.9f * (dvn * a4) + 0.1f * bflo(xv.z);
  float h5 = 0.9f * (dvn * a5) + 0.1f * bfhi(xv.z);
  float h6 = 0.9f * (dvn * a6) + 0.1f * bflo(xv.w);
  float h7 = 0.9f * (dvn * a7) + 0.1f * bfhi(xv.w);

  if (!last) {
    uint4 o;
    o.x = pk(dvn * h0, dvn * h1);
    o.y = pk(dvn * h2, dvn * h3);
    o.z = pk(dvn * h4, dvn * h5);
    o.w = pk(dvn * h6, dvn * h7);
    ((uint4*)(gout + (size_t)node * NCLS))[r] = o;
  } else {
    float mx = fmaxf(fmaxf(fmaxf(h0, h1), fmaxf(h2, h3)),
                     fmaxf(fmaxf(h4, h5), fmaxf(h6, h7)));
#pragma unroll
    for (int off = 1; off < 8; off <<= 1) mx = fmaxf(mx, __shfl_xor(mx, off));
    float s = __expf(h0 - mx) + __expf(h1 - mx) + __expf(h2 - mx) + __expf(h3 - mx) +
              __expf(h4 - mx) + __expf(h5 - mx) + __expf(h6 - mx) + __expf(h7 - mx);
#pragma unroll
    for (int off = 1; off < 8; off <<= 1) s += __shfl_xor(s, off);
    float ls = __logf(s);
    float* op = out + (size_t)node * NCLS + r * 8;
    float4 o0 = {h0 - mx - ls, h1 - mx - ls, h2 - mx - ls, h3 - mx - ls};
    float4 o1 = {h4 - mx - ls, h5 - mx - ls, h6 - mx - ls, h7 - mx - ls};
    *(float4*)(op) = o0;
    *(float4*)(op + 4) = o1;
  }
}

extern "C" void kernel_launch(void* const* d_in, const int* in_sizes, int n_in,
                              void* d_out, int out_size, void* d_ws, size_t ws_size,
                              hipStream_t stream) {
  const float* x  = (const float*)d_in[0];
  const int*   ei = (const int*)d_in[1];
  const float* W1 = (const float*)d_in[2];
  const float* b1 = (const float*)d_in[3];
  const float* W2 = (const float*)d_in[4];
  const float* b2 = (const float*)d_in[5];

  char* ws = (char*)d_ws;
  unsigned short* x0bf   = (unsigned short*)(ws);             // 12.8 MB
  unsigned short* gA     = (unsigned short*)(ws + 12800000);  // 12.8 MB + null row
  unsigned short* gB     = (unsigned short*)(ws + 25600256);  // 12.8 MB + null row
  int*            csrc   = (int*)(ws + 38400384);             // 6.4 MB
  int*            cnt    = (int*)(ws + 44800384);             // 400 KB
  int*            rs     = (int*)(ws + 45200384);             // 400.128 KB
  int*            rs2    = (int*)(ws + 45600512);             // 400 KB
  float*          dinv   = (float*)(ws + 46000512);           // 400 KB
  short*          W1t    = (short*)(ws + 46800512);           // 128 KB
  short*          W2t    = (short*)(ws + 46931584);           // 16 KB
  int*            bsum   = (int*)(ws + 46948096);             // 1.6 KB

  hipMemsetAsync(cnt, 0, 400000, stream);            // only cnt needs zeroing
  // zero null-gather row (index NNODES) in both state buffers
  hipMemsetAsync((char*)gA + (size_t)NNODES * NCLS * 2, 0, 128, stream);
  hipMemsetAsync((char*)gB + (size_t)NNODES * NCLS * 2, 0, 128, stream);

  hist_k<<<2048, 256, 0, stream>>>(ei, cnt);
  scan1_k<<<NB1, 256, 0, stream>>>(cnt, rs, bsum);
  scan2_k<<<1, 512, 0, stream>>>(bsum, rs);
  scan3_k<<<NB1, 256, 0, stream>>>(cnt, bsum, rs, rs2, dinv);
  scatter_k<<<2048, 256, 0, stream>>>(ei, rs2, csrc);

  wt_k<<<(NFEAT * NHID + NHID * NCLS + 255) / 256, 256, 0, stream>>>(W1, W1t, W2, W2t);

  mlp3_k<<<(NNODES + 127) / 128, 512, 0, stream>>>(x, W1t, b1, W2t, b2, dinv, x0bf, gB);

  // g0 in gB; odd t writes gA, even t writes gB; t=10 reads gA, writes d_out (f32)
  for (int t = 1; t <= 10; ++t) {
    const unsigned short* gin = (t & 1) ? gB : gA;
    unsigned short* gout      = (t & 1) ? gA : gB;
    prop_k<<<NNODES / 32, 256, 0, stream>>>(gin, x0bf, dinv, rs, csrc, gout,
                                            (float*)d_out, t == 10);
  }
}

// Round 11
// 526.857 us; speedup vs baseline: 1.0074x; 1.0074x over previous
//
#include <hip/hip_runtime.h>
#include <hip/hip_bf16.h>

typedef __attribute__((ext_vector_type(8))) short s8v;
typedef __attribute__((ext_vector_type(4))) float f4v;

#define NNODES 100000
#define NEDGES 1600000
#define NFEAT 512
#define NHID 128
#define NCLS 64
#define NB1 391   // ceil(NNODES/256)
#define NBUK 49   // ceil(NNODES/2048) dst-buckets

static __device__ __forceinline__ short f2bf(float f) {
  __hip_bfloat16 h = __float2bfloat16(f);
  return __builtin_bit_cast(short, h);
}
static __device__ __forceinline__ float bflo(unsigned int u) {
  return __builtin_bit_cast(float, u << 16);
}
static __device__ __forceinline__ float bfhi(unsigned int u) {
  return __builtin_bit_cast(float, u & 0xFFFF0000u);
}
static __device__ __forceinline__ unsigned int pk(float lo, float hi) {
  return (unsigned int)(unsigned short)f2bf(lo) |
         ((unsigned int)(unsigned short)f2bf(hi) << 16);
}
static __device__ __forceinline__ void glds16(const void* g, void* l) {
  __builtin_amdgcn_global_load_lds(
      (const __attribute__((address_space(1))) unsigned int*)g,
      (__attribute__((address_space(3))) unsigned int*)l, 16, 0, 0);
}

// per-block edge-dtype detection: int64 => odd 32-bit words of first 1024 pairs all zero
static __device__ __forceinline__ bool detect32(const int* __restrict__ ei, int* sm) {
  if (threadIdx.x == 0) *sm = 0;
  __syncthreads();
  int i = threadIdx.x & 255;
  int acc = ei[2 * i + 1] | ei[2 * (i + 256) + 1] |
            ei[2 * (i + 512) + 1] | ei[2 * (i + 768) + 1];
  if (acc != 0) atomicOr(sm, 1);
  __syncthreads();
  return *sm != 0;
}

__global__ __launch_bounds__(256) void hist_k(const int* __restrict__ ei,
                                              int* __restrict__ cnt) {
  __shared__ int sm;
  bool is32 = detect32(ei, &sm);
  int stride = gridDim.x * blockDim.x;
  for (int e = blockIdx.x * blockDim.x + threadIdx.x; e < NEDGES; e += stride) {
    int d = is32 ? ei[NEDGES + e] : ei[2 * NEDGES + 2 * e];
    atomicAdd(&cnt[d], 1);
  }
}

// ---- hierarchical exclusive scan of cnt -> rs (+ rs2 cursor copy, dinv, bucket cursors) ----
__global__ __launch_bounds__(256) void scan1_k(const int* __restrict__ cnt,
                                               int* __restrict__ rs,
                                               int* __restrict__ bsum) {
  __shared__ int sm[256];
  int t = threadIdx.x;
  int i = blockIdx.x * 256 + t;
  int v = (i < NNODES) ? cnt[i] : 0;
  sm[t] = v;
  __syncthreads();
  for (int off = 1; off < 256; off <<= 1) {
    int val = (t >= off) ? sm[t - off] : 0;
    __syncthreads();
    sm[t] += val;
    __syncthreads();
  }
  if (i < NNODES) rs[i] = sm[t] - v;
  if (t == 255) bsum[blockIdx.x] = sm[255];
}

__global__ __launch_bounds__(512) void scan2_k(int* __restrict__ bsum, int* __restrict__ rs) {
  __shared__ int sm[512];
  int t = threadIdx.x;
  int v = (t < NB1) ? bsum[t] : 0;
  sm[t] = v;
  __syncthreads();
  for (int off = 1; off < 512; off <<= 1) {
    int val = (t >= off) ? sm[t - off] : 0;
    __syncthreads();
    sm[t] += val;
    __syncthreads();
  }
  if (t < NB1) bsum[t] = sm[t] - v;
  if (t == 511) rs[NNODES] = sm[511];
}

__global__ __launch_bounds__(256) void scan3_k(const int* __restrict__ cnt,
                                               const int* __restrict__ bsum,
                                               int* __restrict__ rs,
                                               int* __restrict__ rs2,
                                               int* __restrict__ gcur,
                                               float* __restrict__ dinv) {
  int i = blockIdx.x * 256 + threadIdx.x;
  if (i < NNODES) {
    int v = rs[i] + bsum[blockIdx.x];
    rs[i] = v;
    rs2[i] = v;
    if ((i & 2047) == 0) gcur[i >> 11] = v;  // bucket cursor seeds
    dinv[i] = rsqrtf((float)(cnt[i] + 1));
  }
}

// ---- phase 1: bucket edges by dst range into pairbuf (contiguous chunk writes) ----
__global__ __launch_bounds__(256) void bucket_k(const int* __restrict__ ei,
                                                int* __restrict__ gcur,
                                                uint2* __restrict__ pairbuf) {
  __shared__ int sm;
  __shared__ int lcnt[NBUK], gpos[NBUK], loff[NBUK];
  bool is32 = detect32(ei, &sm);
  int t = threadIdx.x;
  int e0 = blockIdx.x * 4096;
  if (t < NBUK) lcnt[t] = 0;
  __syncthreads();
  int s_[16], d_[16];
#pragma unroll
  for (int k = 0; k < 16; ++k) {
    int e = e0 + k * 256 + t;
    int s = -1, d = -1;
    if (e < NEDGES) {
      if (is32) { s = ei[e];     d = ei[NEDGES + e]; }
      else      { s = ei[2 * e]; d = ei[2 * NEDGES + 2 * e]; }
    }
    s_[k] = s; d_[k] = d;
    if (d >= 0) atomicAdd(&lcnt[d >> 11], 1);
  }
  __syncthreads();
  if (t < NBUK) { gpos[t] = atomicAdd(&gcur[t], lcnt[t]); loff[t] = 0; }
  __syncthreads();
#pragma unroll
  for (int k = 0; k < 16; ++k) {
    int d = d_[k];
    if (d >= 0) {
      int b = d >> 11;
      int pos = gpos[b] + atomicAdd(&loff[b], 1);
      uint2 p; p.x = (unsigned)s_[k]; p.y = (unsigned)d;
      pairbuf[pos] = p;
    }
  }
}

// ---- phase 2: scatter within dst-local buckets (L2-resident csrc windows) ----
__global__ __launch_bounds__(256) void scatter2_k(const uint2* __restrict__ pairbuf,
                                                  int* __restrict__ rs2,
                                                  int* __restrict__ csrc) {
  int stride = gridDim.x * blockDim.x;
  for (int i = blockIdx.x * blockDim.x + threadIdx.x; i < NEDGES; i += stride) {
    uint2 p = pairbuf[i];
    int pos = atomicAdd(&rs2[p.y], 1);
    csrc[pos] = (int)p.x;
  }
}

// ---- weight transpose+convert (merged) ----
__global__ __launch_bounds__(256) void wt_k(const float* __restrict__ W1, short* __restrict__ W1t,
                                            const float* __restrict__ W2, short* __restrict__ W2t) {
  int i = blockIdx.x * 256 + threadIdx.x;
  if (i < NFEAT * NHID) {
    int k = i >> 7, c = i & 127;
    W1t[(size_t)c * NFEAT + k] = f2bf(W1[i]);
  } else {
    int j = i - NFEAT * NHID;
    if (j < NHID * NCLS) {
      int k = j >> 6, c = j & 63;
      W2t[(size_t)c * NHID + k] = f2bf(W2[j]);
    }
  }
}

// ---- fused MLP: BM=128, BK=64, 512 threads (8 waves), dbuf LDS A+B ----
__global__ __launch_bounds__(512, 4) void mlp3_k(const float* __restrict__ x,
                                                 const short* __restrict__ W1t,
                                                 const float* __restrict__ b1,
                                                 const short* __restrict__ W2t,
                                                 const float* __restrict__ b2,
                                                 const float* __restrict__ dinv,
                                                 unsigned short* __restrict__ x0,
                                                 unsigned short* __restrict__ g0) {
  __shared__ __align__(16) short As[2][8192]; // 2 x 128 rows x 64 k bf16
  __shared__ __align__(16) short Bs[2][8192]; // 2 x 128 col x 64 k bf16
  int tid = threadIdx.x, lane = tid & 63, wave = tid >> 6;
  int r = lane & 15, q = lane >> 4;
  int G = tid >> 4, li = tid & 15;        // A-staging: 32 row-groups x 16
  int row0 = blockIdx.x * 128;
  int wr = (wave >> 1) * 32, wc = (wave & 1) * 64;
  char* AsB = (char*)As;
  char* BsB = (char*)Bs;

  auto loadA = [&](float4* av, int kk) {
#pragma unroll
    for (int rd = 0; rd < 4; ++rd) {
      int row = rd * 32 + G;
      int grow = row0 + row; if (grow >= NNODES) grow = NNODES - 1;
      av[rd] = *reinterpret_cast<const float4*>(x + (size_t)grow * NFEAT + kk + li * 4);
    }
  };
  auto writeA = [&](const float4* av, int buf) {
#pragma unroll
    for (int rd = 0; rd < 4; ++rd) {
      int row = rd * 32 + G;
      uint2 u;
      u.x = pk(av[rd].x, av[rd].y);
      u.y = pk(av[rd].z, av[rd].w);
      *(uint2*)(AsB + buf * 16384 + row * 128 + (((li >> 1) ^ (row & 7)) << 4) + (li & 1) * 8) = u;
    }
  };
  auto stageB = [&](int buf, int kk) {
#pragma unroll
    for (int i2 = 0; i2 < 2; ++i2) {
      int i = wave * 2 + i2;
      int col = i * 8 + (lane >> 3);
      int srcg = (lane & 7) ^ (col & 7);
      glds16(W1t + (size_t)col * NFEAT + kk + srcg * 8, BsB + buf * 16384 + i * 1024);
    }
  };

  f4v acc[2][4];
#pragma unroll
  for (int a = 0; a < 2; ++a)
#pragma unroll
    for (int b = 0; b < 4; ++b) acc[a][b] = (f4v){0.f, 0.f, 0.f, 0.f};

  {
    float4 av[4];
    loadA(av, 0);
    stageB(0, 0);
    writeA(av, 0);
  }
  __syncthreads();

  int cur = 0;
  for (int c = 0; c < 8; ++c) {
    float4 av[4];
    if (c < 7) {               // issue next-tile loads early (T14)
      loadA(av, (c + 1) * 64);
      stageB(cur ^ 1, (c + 1) * 64);
    }
#pragma unroll
    for (int kc = 0; kc < 2; ++kc) {
      s8v af[2], bfr[4];
#pragma unroll
      for (int rt = 0; rt < 2; ++rt) {
        int arow = wr + rt * 16 + r;
        af[rt] = *(const s8v*)(AsB + cur * 16384 + arow * 128 +
                               (((kc * 4 + q) ^ (arow & 7)) << 4));
      }
#pragma unroll
      for (int ct = 0; ct < 4; ++ct) {
        int bcol = wc + ct * 16 + r;
        bfr[ct] = *(const s8v*)(BsB + cur * 16384 + bcol * 128 +
                                (((kc * 4 + q) ^ (bcol & 7)) << 4));
      }
#pragma unroll
      for (int rt = 0; rt < 2; ++rt)
#pragma unroll
        for (int ct = 0; ct < 4; ++ct)
          acc[rt][ct] = __builtin_amdgcn_mfma_f32_16x16x32_bf16(af[rt], bfr[ct], acc[rt][ct], 0, 0, 0);
    }
    if (c < 7) writeA(av, cur ^ 1);  // write-late
    __syncthreads();
    cur ^= 1;
  }

  // ---- h1 tile (relu, bf16) -> LDS (256B swizzled rows over As) ----
  {
    float bias1[4];
#pragma unroll
    for (int ct = 0; ct < 4; ++ct) bias1[ct] = b1[wc + ct * 16 + r];
#pragma unroll
    for (int rt = 0; rt < 2; ++rt)
#pragma unroll
      for (int ct = 0; ct < 4; ++ct) {
        int col = wc + ct * 16 + r;
#pragma unroll
        for (int j = 0; j < 4; ++j) {
          int row = wr + rt * 16 + q * 4 + j;
          float v = acc[rt][ct][j] + bias1[ct];
          v = v > 0.f ? v : 0.f;
          *(short*)(AsB + row * 256 + (((col >> 3) ^ (row & 15)) << 4) + (col & 7) * 2) = f2bf(v);
        }
      }
  }
  __syncthreads();

  // ---- gemm2: h1[128x128] @ W2t; wave: 32 rows x 32 cols ----
  int wc2 = (wave & 1) * 32;
  f4v acc2[2][2];
#pragma unroll
  for (int a = 0; a < 2; ++a)
#pragma unroll
    for (int b = 0; b < 2; ++b) acc2[a][b] = (f4v){0.f, 0.f, 0.f, 0.f};
#pragma unroll
  for (int kc = 0; kc < 4; ++kc) {
    s8v a2[2], b2f[2];
#pragma unroll
    for (int rt = 0; rt < 2; ++rt) {
      int row = wr + rt * 16 + r;
      a2[rt] = *(const s8v*)(AsB + row * 256 + (((kc * 4 + q) ^ (row & 15)) << 4));
    }
#pragma unroll
    for (int ct = 0; ct < 2; ++ct) {
      int col2 = wc2 + ct * 16 + r;
      b2f[ct] = *(const s8v*)(W2t + (size_t)col2 * NHID + kc * 32 + q * 8);
    }
#pragma unroll
    for (int rt = 0; rt < 2; ++rt)
#pragma unroll
      for (int ct = 0; ct < 2; ++ct)
        acc2[rt][ct] = __builtin_amdgcn_mfma_f32_16x16x32_bf16(a2[rt], b2f[ct], acc2[rt][ct], 0, 0, 0);
  }

  // ---- epilogue: pack x0/g0 into Bs (swizzled 128B rows), coalesced stores ----
  {
    float bias2[2];
#pragma unroll
    for (int ct = 0; ct < 2; ++ct) bias2[ct] = b2[wc2 + ct * 16 + r];
#pragma unroll
    for (int rt = 0; rt < 2; ++rt)
#pragma unroll
      for (int j = 0; j < 4; ++j) {
        int row = wr + rt * 16 + q * 4 + j;
        int grow = row0 + row;
        float dv = dinv[grow < NNODES ? grow : NNODES - 1];
#pragma unroll
        for (int ct = 0; ct < 2; ++ct) {
          float hh = acc2[rt][ct][j] + bias2[ct];
          int col = wc2 + ct * 16 + r;
          int byte = row * 128 + (((col >> 3) ^ (row & 7)) << 4) + (col & 7) * 2;
          *(short*)(BsB + byte) = f2bf(hh);
          *(short*)(BsB + 16384 + byte) = f2bf(dv * hh);
        }
      }
  }
  __syncthreads();
#pragma unroll
  for (int rd = 0; rd < 4; ++rd) {
    int row = rd * 32 + G;
    int grow = row0 + row;
    if (grow < NNODES) {
      int byte = row * 128 + (((li >> 1) ^ (row & 7)) << 4) + (li & 1) * 8;
      uint2 vx = *(const uint2*)(BsB + byte);
      uint2 vg = *(const uint2*)(BsB + 16384 + byte);
      *(uint2*)(x0 + (size_t)grow * NCLS + li * 4) = vx;
      *(uint2*)(g0 + (size_t)grow * NCLS + li * 4) = vg;
    }
  }
}

// ---- propagation: 8 nodes/wave, 8 lanes/node, uint4 gathers, pipelined csrc ----
__global__ __launch_bounds__(256) void prop_k(const unsigned short* __restrict__ gin,
                                              const unsigned short* __restrict__ x0,
                                              const float* __restrict__ dinv,
                                              const int* __restrict__ rs,
                                              const int* __restrict__ csrc,
                                              unsigned short* __restrict__ gout,
                                              float* __restrict__ out,
                                              int last) {
  int tid = threadIdx.x;
  int lane = tid & 63;
  int r = lane & 7;        // 8 lanes per node
  int gbase = lane & 56;
  int node = blockIdx.x * 32 + (tid >> 6) * 8 + (lane >> 3); // 3125*32 == NNODES
  int b = rs[node];
  int deg = rs[node + 1] - b;

  // hoisted loop-invariant loads (issue early)
  uint4 sv = ((const uint4*)(gin + (size_t)node * NCLS))[r];
  uint4 xv = ((const uint4*)(x0 + (size_t)node * NCLS))[r];
  float dvn = dinv[node];

  float a0 = bflo(sv.x), a1 = bfhi(sv.x), a2 = bflo(sv.y), a3 = bfhi(sv.y);
  float a4 = bflo(sv.z), a5 = bfhi(sv.z), a6 = bflo(sv.w), a7 = bfhi(sv.w);

  int m = deg;  // wave-uniform max
  m = max(m, __shfl_xor(m, 8));
  m = max(m, __shfl_xor(m, 16));
  m = max(m, __shfl_xor(m, 32));

  // software-pipelined index chunks: prefetch chunk k+1 while gathering chunk k
  int idx = NNODES;                       // null row (zeroed)
  if (r < deg) idx = csrc[b + r];
  for (int basek = 0; basek < m; basek += 8) {
    int nidx = NNODES;
    if (basek + 8 + r < deg) nidx = csrc[b + basek + 8 + r];
#pragma unroll
    for (int j = 0; j < 8; ++j) {
      int sj = __shfl(idx, gbase + j);
      uint4 v = ((const uint4*)(gin + (size_t)sj * NCLS))[r];
      a0 += bflo(v.x); a1 += bfhi(v.x); a2 += bflo(v.y); a3 += bfhi(v.y);
      a4 += bflo(v.z); a5 += bfhi(v.z); a6 += bflo(v.w); a7 += bfhi(v.w);
    }
    idx = nidx;
  }

  float h0 = 0.9f * (dvn * a0) + 0.1f * bflo(xv.x);
  float h1 = 0.9f * (dvn * a1) + 0.1f * bfhi(xv.x);
  float h2 = 0.9f * (dvn * a2) + 0.1f * bflo(xv.y);
  float h3 = 0.9f * (dvn * a3) + 0.1f * bfhi(xv.y);
  float h4 = 0.9f * (dvn * a4) + 0.1f * bflo(xv.z);
  float h5 = 0.9f * (dvn * a5) + 0.1f * bfhi(xv.z);
  float h6 = 0.9f * (dvn * a6) + 0.1f * bflo(xv.w);
  float h7 = 0.9f * (dvn * a7) + 0.1f * bfhi(xv.w);

  if (!last) {
    uint4 o;
    o.x = pk(dvn * h0, dvn * h1);
    o.y = pk(dvn * h2, dvn * h3);
    o.z = pk(dvn * h4, dvn * h5);
    o.w = pk(dvn * h6, dvn * h7);
    ((uint4*)(gout + (size_t)node * NCLS))[r] = o;
  } else {
    float mx = fmaxf(fmaxf(fmaxf(h0, h1), fmaxf(h2, h3)),
                     fmaxf(fmaxf(h4, h5), fmaxf(h6, h7)));
#pragma unroll
    for (int off = 1; off < 8; off <<= 1) mx = fmaxf(mx, __shfl_xor(mx, off));
    float s = __expf(h0 - mx) + __expf(h1 - mx) + __expf(h2 - mx) + __expf(h3 - mx) +
              __expf(h4 - mx) + __expf(h5 - mx) + __expf(h6 - mx) + __expf(h7 - mx);
#pragma unroll
    for (int off = 1; off < 8; off <<= 1) s += __shfl_xor(s, off);
    float ls = __logf(s);
    float* op = out + (size_t)node * NCLS + r * 8;
    float4 o0 = {h0 - mx - ls, h1 - mx - ls, h2 - mx - ls, h3 - mx - ls};
    float4 o1 = {h4 - mx - ls, h5 - mx - ls, h6 - mx - ls, h7 - mx - ls};
    *(float4*)(op) = o0;
    *(float4*)(op + 4) = o1;
  }
}

extern "C" void kernel_launch(void* const* d_in, const int* in_sizes, int n_in,
                              void* d_out, int out_size, void* d_ws, size_t ws_size,
                              hipStream_t stream) {
  const float* x  = (const float*)d_in[0];
  const int*   ei = (const int*)d_in[1];
  const float* W1 = (const float*)d_in[2];
  const float* b1 = (const float*)d_in[3];
  const float* W2 = (const float*)d_in[4];
  const float* b2 = (const float*)d_in[5];

  char* ws = (char*)d_ws;
  unsigned short* x0bf   = (unsigned short*)(ws);             // 12.8 MB
  uint2*          pairbuf= (uint2*)(ws);                      // aliases x0bf (used pre-mlp3)
  unsigned short* gA     = (unsigned short*)(ws + 12800000);  // 12.8 MB + null row
  unsigned short* gB     = (unsigned short*)(ws + 25600256);  // 12.8 MB + null row
  int*            csrc   = (int*)(ws + 38400384);             // 6.4 MB
  int*            cnt    = (int*)(ws + 44800384);             // 400 KB
  int*            rs     = (int*)(ws + 45200384);             // 400.128 KB
  int*            rs2    = (int*)(ws + 45600512);             // 400 KB
  float*          dinv   = (float*)(ws + 46000512);           // 400 KB
  short*          W1t    = (short*)(ws + 46800512);           // 128 KB
  short*          W2t    = (short*)(ws + 46931584);           // 16 KB
  int*            bsum   = (int*)(ws + 46948096);             // 1.6 KB
  int*            gcur   = (int*)(ws + 46950144);             // 49 ints

  hipMemsetAsync(cnt, 0, 400000, stream);            // only cnt needs zeroing
  // zero null-gather row (index NNODES) in both state buffers
  hipMemsetAsync((char*)gA + (size_t)NNODES * NCLS * 2, 0, 128, stream);
  hipMemsetAsync((char*)gB + (size_t)NNODES * NCLS * 2, 0, 128, stream);

  hist_k<<<2048, 256, 0, stream>>>(ei, cnt);
  scan1_k<<<NB1, 256, 0, stream>>>(cnt, rs, bsum);
  scan2_k<<<1, 512, 0, stream>>>(bsum, rs);
  scan3_k<<<NB1, 256, 0, stream>>>(cnt, bsum, rs, rs2, gcur, dinv);
  bucket_k<<<(NEDGES + 4095) / 4096, 256, 0, stream>>>(ei, gcur, pairbuf);
  scatter2_k<<<2048, 256, 0, stream>>>(pairbuf, rs2, csrc);

  wt_k<<<(NFEAT * NHID + NHID * NCLS + 255) / 256, 256, 0, stream>>>(W1, W1t, W2, W2t);

  mlp3_k<<<(NNODES + 127) / 128, 512, 0, stream>>>(x, W1t, b1, W2t, b2, dinv, x0bf, gB);

  // g0 in gB; odd t writes gA, even t writes gB; t=10 reads gA, writes d_out (f32)
  for (int t = 1; t <= 10; ++t) {
    const unsigned short* gin = (t & 1) ? gB : gA;
    unsigned short* gout      = (t & 1) ? gA : gB;
    prop_k<<<NNODES / 32, 256, 0, stream>>>(gin, x0bf, dinv, rs, csrc, gout,
                                            (float*)d_out, t == 10);
  }
}

// Round 12
// 425.173 us; speedup vs baseline: 1.2484x; 1.2392x over previous
//
#include <hip/hip_runtime.h>
#include <hip/hip_bf16.h>

typedef __attribute__((ext_vector_type(8))) short s8v;
typedef __attribute__((ext_vector_type(4))) float f4v;

#define NNODES 100000
#define NEDGES 1600000
#define NFEAT 512
#define NHID 128
#define NCLS 64
#define NBUK 49        // ceil(NNODES/2048) dst-buckets
#define CAP 36864      // bucket capacity (mean 32768, +22 sigma)

static __device__ __forceinline__ short f2bf(float f) {
  __hip_bfloat16 h = __float2bfloat16(f);
  return __builtin_bit_cast(short, h);
}
static __device__ __forceinline__ float bflo(unsigned int u) {
  return __builtin_bit_cast(float, u << 16);
}
static __device__ __forceinline__ float bfhi(unsigned int u) {
  return __builtin_bit_cast(float, u & 0xFFFF0000u);
}
static __device__ __forceinline__ unsigned int pk(float lo, float hi) {
  return (unsigned int)(unsigned short)f2bf(lo) |
         ((unsigned int)(unsigned short)f2bf(hi) << 16);
}
static __device__ __forceinline__ void glds16(const void* g, void* l) {
  __builtin_amdgcn_global_load_lds(
      (const __attribute__((address_space(1))) unsigned int*)g,
      (__attribute__((address_space(3))) unsigned int*)l, 16, 0, 0);
}

// per-block edge-dtype detection: int64 => odd 32-bit words of first 1024 pairs all zero
static __device__ __forceinline__ bool detect32(const int* __restrict__ ei, int* sm) {
  if (threadIdx.x == 0) *sm = 0;
  __syncthreads();
  int i = threadIdx.x & 255;
  int acc = ei[2 * i + 1] | ei[2 * (i + 256) + 1] |
            ei[2 * (i + 512) + 1] | ei[2 * (i + 768) + 1];
  if (acc != 0) atomicOr(sm, 1);
  __syncthreads();
  return *sm != 0;
}

__global__ __launch_bounds__(64) void init_k(int* __restrict__ gcur) {
  int t = threadIdx.x;
  if (t < NBUK) gcur[t] = t * CAP;
}

// ---- phase 1: bucket edges by dst range into fixed-capacity regions ----
__global__ __launch_bounds__(256) void bucket_k(const int* __restrict__ ei,
                                                int* __restrict__ gcur,
                                                uint2* __restrict__ pairbuf) {
  __shared__ int sm;
  __shared__ int lcnt[NBUK], gpos[NBUK], loff[NBUK];
  bool is32 = detect32(ei, &sm);
  int t = threadIdx.x;
  int e0 = blockIdx.x * 4096;
  if (t < NBUK) lcnt[t] = 0;
  __syncthreads();
  int s_[16], d_[16];
#pragma unroll
  for (int k = 0; k < 16; ++k) {
    int e = e0 + k * 256 + t;
    int s = -1, d = -1;
    if (e < NEDGES) {
      if (is32) { s = ei[e];     d = ei[NEDGES + e]; }
      else      { s = ei[2 * e]; d = ei[2 * NEDGES + 2 * e]; }
    }
    s_[k] = s; d_[k] = d;
    if (d >= 0) atomicAdd(&lcnt[d >> 11], 1);
  }
  __syncthreads();
  if (t < NBUK) { gpos[t] = atomicAdd(&gcur[t], lcnt[t]); loff[t] = 0; }
  __syncthreads();
#pragma unroll
  for (int k = 0; k < 16; ++k) {
    int d = d_[k];
    if (d >= 0) {
      int b = d >> 11;
      int pos = gpos[b] + atomicAdd(&loff[b], 1);
      if (pos < (b + 1) * CAP) {  // safety vs capacity overflow
        uint2 p; p.x = (unsigned)s_[k]; p.y = (unsigned)d;
        pairbuf[pos] = p;
      }
    }
  }
}

// ---- phase 2: per-bucket CSR finalize: count, scan, rs/dinv, LDS-cursor scatter ----
__global__ __launch_bounds__(1024) void csr_k(const uint2* __restrict__ pairbuf,
                                              const int* __restrict__ gcur,
                                              int* __restrict__ rs,
                                              float* __restrict__ dinv,
                                              int* __restrict__ csrc) {
  __shared__ int lcnt[2048];   // counts, then reused as global-position cursors
  __shared__ int lscan[1024];
  __shared__ int sizes[NBUK];
  int t = threadIdx.x, b = blockIdx.x;
  int nbase = b * 2048;
  if (t < NBUK) sizes[t] = gcur[t] - t * CAP;
  lcnt[t] = 0; lcnt[t + 1024] = 0;
  __syncthreads();
  int nb = sizes[b];
  int gbase = 0;
  for (int j = 0; j < b; ++j) gbase += sizes[j];  // uniform small loop
  const uint2* mybuf = pairbuf + (size_t)b * CAP;

  // count
  for (int i = t; i < nb; i += 1024)
    atomicAdd(&lcnt[mybuf[i].y & 2047], 1);
  __syncthreads();

  // exclusive scan of 2048 counts (pairs per thread)
  int c0 = lcnt[2 * t], c1 = lcnt[2 * t + 1];
  lscan[t] = c0 + c1;
  __syncthreads();
  for (int off = 1; off < 1024; off <<= 1) {
    int v = (t >= off) ? lscan[t - off] : 0;
    __syncthreads();
    lscan[t] += v;
    __syncthreads();
  }
  int ex = lscan[t] - (c0 + c1);
  int r0 = gbase + ex, r1 = r0 + c0;
  int node0 = nbase + 2 * t, node1 = node0 + 1;
  if (node0 < NNODES) { rs[node0] = r0; dinv[node0] = rsqrtf((float)(c0 + 1)); }
  if (node1 < NNODES) { rs[node1] = r1; dinv[node1] = rsqrtf((float)(c1 + 1)); }
  if (b == NBUK - 1 && t == 1023) rs[NNODES] = NEDGES;
  __syncthreads();           // all reads of lcnt-as-counts done
  lcnt[2 * t] = r0; lcnt[2 * t + 1] = r1;  // cursors
  __syncthreads();

  // scatter within this bucket's csrc window (single CU / single L2)
  for (int i = t; i < nb; i += 1024) {
    uint2 p = mybuf[i];
    int pos = atomicAdd(&lcnt[p.y & 2047], 1);
    csrc[pos] = (int)p.x;
  }
}

// ---- weight transpose+convert (merged) ----
__global__ __launch_bounds__(256) void wt_k(const float* __restrict__ W1, short* __restrict__ W1t,
                                            const float* __restrict__ W2, short* __restrict__ W2t) {
  int i = blockIdx.x * 256 + threadIdx.x;
  if (i < NFEAT * NHID) {
    int k = i >> 7, c = i & 127;
    W1t[(size_t)c * NFEAT + k] = f2bf(W1[i]);
  } else {
    int j = i - NFEAT * NHID;
    if (j < NHID * NCLS) {
      int k = j >> 6, c = j & 63;
      W2t[(size_t)c * NHID + k] = f2bf(W2[j]);
    }
  }
}

// ---- fused MLP: BM=128, BK=64, 512 threads (8 waves), dbuf LDS A+B ----
__global__ __launch_bounds__(512, 4) void mlp3_k(const float* __restrict__ x,
                                                 const short* __restrict__ W1t,
                                                 const float* __restrict__ b1,
                                                 const short* __restrict__ W2t,
                                                 const float* __restrict__ b2,
                                                 const float* __restrict__ dinv,
                                                 unsigned short* __restrict__ x0,
                                                 unsigned short* __restrict__ g0) {
  __shared__ __align__(16) short As[2][8192]; // 2 x 128 rows x 64 k bf16
  __shared__ __align__(16) short Bs[2][8192]; // 2 x 128 col x 64 k bf16
  int tid = threadIdx.x, lane = tid & 63, wave = tid >> 6;
  int r = lane & 15, q = lane >> 4;
  int G = tid >> 4, li = tid & 15;        // A-staging: 32 row-groups x 16
  int row0 = blockIdx.x * 128;
  int wr = (wave >> 1) * 32, wc = (wave & 1) * 64;
  char* AsB = (char*)As;
  char* BsB = (char*)Bs;

  auto loadA = [&](float4* av, int kk) {
#pragma unroll
    for (int rd = 0; rd < 4; ++rd) {
      int row = rd * 32 + G;
      int grow = row0 + row; if (grow >= NNODES) grow = NNODES - 1;
      av[rd] = *reinterpret_cast<const float4*>(x + (size_t)grow * NFEAT + kk + li * 4);
    }
  };
  auto writeA = [&](const float4* av, int buf) {
#pragma unroll
    for (int rd = 0; rd < 4; ++rd) {
      int row = rd * 32 + G;
      uint2 u;
      u.x = pk(av[rd].x, av[rd].y);
      u.y = pk(av[rd].z, av[rd].w);
      *(uint2*)(AsB + buf * 16384 + row * 128 + (((li >> 1) ^ (row & 7)) << 4) + (li & 1) * 8) = u;
    }
  };
  auto stageB = [&](int buf, int kk) {
#pragma unroll
    for (int i2 = 0; i2 < 2; ++i2) {
      int i = wave * 2 + i2;
      int col = i * 8 + (lane >> 3);
      int srcg = (lane & 7) ^ (col & 7);
      glds16(W1t + (size_t)col * NFEAT + kk + srcg * 8, BsB + buf * 16384 + i * 1024);
    }
  };

  f4v acc[2][4];
#pragma unroll
  for (int a = 0; a < 2; ++a)
#pragma unroll
    for (int b = 0; b < 4; ++b) acc[a][b] = (f4v){0.f, 0.f, 0.f, 0.f};

  {
    float4 av[4];
    loadA(av, 0);
    stageB(0, 0);
    writeA(av, 0);
  }
  __syncthreads();

  int cur = 0;
  for (int c = 0; c < 8; ++c) {
    float4 av[4];
    if (c < 7) {               // issue next-tile loads early (T14)
      loadA(av, (c + 1) * 64);
      stageB(cur ^ 1, (c + 1) * 64);
    }
#pragma unroll
    for (int kc = 0; kc < 2; ++kc) {
      s8v af[2], bfr[4];
#pragma unroll
      for (int rt = 0; rt < 2; ++rt) {
        int arow = wr + rt * 16 + r;
        af[rt] = *(const s8v*)(AsB + cur * 16384 + arow * 128 +
                               (((kc * 4 + q) ^ (arow & 7)) << 4));
      }
#pragma unroll
      for (int ct = 0; ct < 4; ++ct) {
        int bcol = wc + ct * 16 + r;
        bfr[ct] = *(const s8v*)(BsB + cur * 16384 + bcol * 128 +
                                (((kc * 4 + q) ^ (bcol & 7)) << 4));
      }
#pragma unroll
      for (int rt = 0; rt < 2; ++rt)
#pragma unroll
        for (int ct = 0; ct < 4; ++ct)
          acc[rt][ct] = __builtin_amdgcn_mfma_f32_16x16x32_bf16(af[rt], bfr[ct], acc[rt][ct], 0, 0, 0);
    }
    if (c < 7) writeA(av, cur ^ 1);  // write-late
    __syncthreads();
    cur ^= 1;
  }

  // ---- h1 tile (relu, bf16) -> LDS (256B swizzled rows over As) ----
  {
    float bias1[4];
#pragma unroll
    for (int ct = 0; ct < 4; ++ct) bias1[ct] = b1[wc + ct * 16 + r];
#pragma unroll
    for (int rt = 0; rt < 2; ++rt)
#pragma unroll
      for (int ct = 0; ct < 4; ++ct) {
        int col = wc + ct * 16 + r;
#pragma unroll
        for (int j = 0; j < 4; ++j) {
          int row = wr + rt * 16 + q * 4 + j;
          float v = acc[rt][ct][j] + bias1[ct];
          v = v > 0.f ? v : 0.f;
          *(short*)(AsB + row * 256 + (((col >> 3) ^ (row & 15)) << 4) + (col & 7) * 2) = f2bf(v);
        }
      }
  }
  __syncthreads();

  // ---- gemm2: h1[128x128] @ W2t; wave: 32 rows x 32 cols ----
  int wc2 = (wave & 1) * 32;
  f4v acc2[2][2];
#pragma unroll
  for (int a = 0; a < 2; ++a)
#pragma unroll
    for (int b = 0; b < 2; ++b) acc2[a][b] = (f4v){0.f, 0.f, 0.f, 0.f};
#pragma unroll
  for (int kc = 0; kc < 4; ++kc) {
    s8v a2[2], b2f[2];
#pragma unroll
    for (int rt = 0; rt < 2; ++rt) {
      int row = wr + rt * 16 + r;
      a2[rt] = *(const s8v*)(AsB + row * 256 + (((kc * 4 + q) ^ (row & 15)) << 4));
    }
#pragma unroll
    for (int ct = 0; ct < 2; ++ct) {
      int col2 = wc2 + ct * 16 + r;
      b2f[ct] = *(const s8v*)(W2t + (size_t)col2 * NHID + kc * 32 + q * 8);
    }
#pragma unroll
    for (int rt = 0; rt < 2; ++rt)
#pragma unroll
      for (int ct = 0; ct < 2; ++ct)
        acc2[rt][ct] = __builtin_amdgcn_mfma_f32_16x16x32_bf16(a2[rt], b2f[ct], acc2[rt][ct], 0, 0, 0);
  }

  // ---- epilogue: pack x0/g0 into Bs (swizzled 128B rows), coalesced stores ----
  {
    float bias2[2];
#pragma unroll
    for (int ct = 0; ct < 2; ++ct) bias2[ct] = b2[wc2 + ct * 16 + r];
#pragma unroll
    for (int rt = 0; rt < 2; ++rt)
#pragma unroll
      for (int j = 0; j < 4; ++j) {
        int row = wr + rt * 16 + q * 4 + j;
        int grow = row0 + row;
        float dv = dinv[grow < NNODES ? grow : NNODES - 1];
#pragma unroll
        for (int ct = 0; ct < 2; ++ct) {
          float hh = acc2[rt][ct][j] + bias2[ct];
          int col = wc2 + ct * 16 + r;
          int byte = row * 128 + (((col >> 3) ^ (row & 7)) << 4) + (col & 7) * 2;
          *(short*)(BsB + byte) = f2bf(hh);
          *(short*)(BsB + 16384 + byte) = f2bf(dv * hh);
        }
      }
  }
  __syncthreads();
#pragma unroll
  for (int rd = 0; rd < 4; ++rd) {
    int row = rd * 32 + G;
    int grow = row0 + row;
    if (grow < NNODES) {
      int byte = row * 128 + (((li >> 1) ^ (row & 7)) << 4) + (li & 1) * 8;
      uint2 vx = *(const uint2*)(BsB + byte);
      uint2 vg = *(const uint2*)(BsB + 16384 + byte);
      *(uint2*)(x0 + (size_t)grow * NCLS + li * 4) = vx;
      *(uint2*)(g0 + (size_t)grow * NCLS + li * 4) = vg;
    }
  }
}

// ---- propagation: 8 nodes/wave, 8 lanes/node, uint4 gathers, pipelined csrc ----
__global__ __launch_bounds__(256) void prop_k(const unsigned short* __restrict__ gin,
                                              const unsigned short* __restrict__ x0,
                                              const float* __restrict__ dinv,
                                              const int* __restrict__ rs,
                                              const int* __restrict__ csrc,
                                              unsigned short* __restrict__ gout,
                                              float* __restrict__ out,
                                              int last) {
  int tid = threadIdx.x;
  int lane = tid & 63;
  int r = lane & 7;        // 8 lanes per node
  int gbase = lane & 56;
  int node = blockIdx.x * 32 + (tid >> 6) * 8 + (lane >> 3); // 3125*32 == NNODES
  int b = rs[node];
  int deg = rs[node + 1] - b;

  // hoisted loop-invariant loads (issue early)
  uint4 sv = ((const uint4*)(gin + (size_t)node * NCLS))[r];
  uint4 xv = ((const uint4*)(x0 + (size_t)node * NCLS))[r];
  float dvn = dinv[node];

  float a0 = bflo(sv.x), a1 = bfhi(sv.x), a2 = bflo(sv.y), a3 = bfhi(sv.y);
  float a4 = bflo(sv.z), a5 = bfhi(sv.z), a6 = bflo(sv.w), a7 = bfhi(sv.w);

  int m = deg;  // wave-uniform max
  m = max(m, __shfl_xor(m, 8));
  m = max(m, __shfl_xor(m, 16));
  m = max(m, __shfl_xor(m, 32));

  // software-pipelined index chunks: prefetch chunk k+1 while gathering chunk k
  int idx = NNODES;                       // null row (zeroed)
  if (r < deg) idx = csrc[b + r];
  for (int basek = 0; basek < m; basek += 8) {
    int nidx = NNODES;
    if (basek + 8 + r < deg) nidx = csrc[b + basek + 8 + r];
#pragma unroll
    for (int j = 0; j < 8; ++j) {
      int sj = __shfl(idx, gbase + j);
      uint4 v = ((const uint4*)(gin + (size_t)sj * NCLS))[r];
      a0 += bflo(v.x); a1 += bfhi(v.x); a2 += bflo(v.y); a3 += bfhi(v.y);
      a4 += bflo(v.z); a5 += bfhi(v.z); a6 += bflo(v.w); a7 += bfhi(v.w);
    }
    idx = nidx;
  }

  float h0 = 0.9f * (dvn * a0) + 0.1f * bflo(xv.x);
  float h1 = 0.9f * (dvn * a1) + 0.1f * bfhi(xv.x);
  float h2 = 0.9f * (dvn * a2) + 0.1f * bflo(xv.y);
  float h3 = 0.9f * (dvn * a3) + 0.1f * bfhi(xv.y);
  float h4 = 0.9f * (dvn * a4) + 0.1f * bflo(xv.z);
  float h5 = 0.9f * (dvn * a5) + 0.1f * bfhi(xv.z);
  float h6 = 0.9f * (dvn * a6) + 0.1f * bflo(xv.w);
  float h7 = 0.9f * (dvn * a7) + 0.1f * bfhi(xv.w);

  if (!last) {
    uint4 o;
    o.x = pk(dvn * h0, dvn * h1);
    o.y = pk(dvn * h2, dvn * h3);
    o.z = pk(dvn * h4, dvn * h5);
    o.w = pk(dvn * h6, dvn * h7);
    ((uint4*)(gout + (size_t)node * NCLS))[r] = o;
  } else {
    float mx = fmaxf(fmaxf(fmaxf(h0, h1), fmaxf(h2, h3)),
                     fmaxf(fmaxf(h4, h5), fmaxf(h6, h7)));
#pragma unroll
    for (int off = 1; off < 8; off <<= 1) mx = fmaxf(mx, __shfl_xor(mx, off));
    float s = __expf(h0 - mx) + __expf(h1 - mx) + __expf(h2 - mx) + __expf(h3 - mx) +
              __expf(h4 - mx) + __expf(h5 - mx) + __expf(h6 - mx) + __expf(h7 - mx);
#pragma unroll
    for (int off = 1; off < 8; off <<= 1) s += __shfl_xor(s, off);
    float ls = __logf(s);
    float* op = out + (size_t)node * NCLS + r * 8;
    float4 o0 = {h0 - mx - ls, h1 - mx - ls, h2 - mx - ls, h3 - mx - ls};
    float4 o1 = {h4 - mx - ls, h5 - mx - ls, h6 - mx - ls, h7 - mx - ls};
    *(float4*)(op) = o0;
    *(float4*)(op + 4) = o1;
  }
}

extern "C" void kernel_launch(void* const* d_in, const int* in_sizes, int n_in,
                              void* d_out, int out_size, void* d_ws, size_t ws_size,
                              hipStream_t stream) {
  const float* x  = (const float*)d_in[0];
  const int*   ei = (const int*)d_in[1];
  const float* W1 = (const float*)d_in[2];
  const float* b1 = (const float*)d_in[3];
  const float* W2 = (const float*)d_in[4];
  const float* b2 = (const float*)d_in[5];

  char* ws = (char*)d_ws;
  unsigned short* x0bf   = (unsigned short*)(ws);             // 12.8 MB (after CSR build)
  uint2*          pairbuf= (uint2*)(ws);                      // 14.45 MB, pre-mlp3 only
  unsigned short* gA     = (unsigned short*)(ws + 12800000);  // 12.8 MB + null row
  unsigned short* gB     = (unsigned short*)(ws + 25600256);  // 12.8 MB + null row
  int*            csrc   = (int*)(ws + 38400384);             // 6.4 MB
  int*            rs     = (int*)(ws + 45200384);             // 400.128 KB
  float*          dinv   = (float*)(ws + 46000512);           // 400 KB
  short*          W1t    = (short*)(ws + 46800512);           // 128 KB
  short*          W2t    = (short*)(ws + 46931584);           // 16 KB
  int*            gcur   = (int*)(ws + 46950144);             // 49 ints

  // zero null-gather row (index NNODES) in both state buffers
  hipMemsetAsync((char*)gA + (size_t)NNODES * NCLS * 2, 0, 128, stream);
  hipMemsetAsync((char*)gB + (size_t)NNODES * NCLS * 2, 0, 128, stream);

  init_k<<<1, 64, 0, stream>>>(gcur);
  bucket_k<<<(NEDGES + 4095) / 4096, 256, 0, stream>>>(ei, gcur, pairbuf);
  csr_k<<<NBUK, 1024, 0, stream>>>(pairbuf, gcur, rs, dinv, csrc);

  wt_k<<<(NFEAT * NHID + NHID * NCLS + 255) / 256, 256, 0, stream>>>(W1, W1t, W2, W2t);

  mlp3_k<<<(NNODES + 127) / 128, 512, 0, stream>>>(x, W1t, b1, W2t, b2, dinv, x0bf, gB);

  // g0 in gB; odd t writes gA, even t writes gB; t=10 reads gA, writes d_out (f32)
  for (int t = 1; t <= 10; ++t) {
    const unsigned short* gin = (t & 1) ? gB : gA;
    unsigned short* gout      = (t & 1) ? gA : gB;
    prop_k<<<NNODES / 32, 256, 0, stream>>>(gin, x0bf, dinv, rs, csrc, gout,
                                            (float*)d_out, t == 10);
  }
}

// Round 13
// 403.636 us; speedup vs baseline: 1.3150x; 1.0534x over previous
//
#include <hip/hip_runtime.h>
#include <hip/hip_bf16.h>

typedef __attribute__((ext_vector_type(8))) short s8v;
typedef __attribute__((ext_vector_type(4))) float f4v;

#define NNODES 100000
#define NEDGES 1600000
#define NFEAT 512
#define NHID 128
#define NCLS 64
#define NBUK 196       // ceil(NNODES/512) dst-buckets of 512 nodes
#define CAP 9216       // bucket capacity (mean 8163, +11 sigma)

static __device__ __forceinline__ short f2bf(float f) {
  __hip_bfloat16 h = __float2bfloat16(f);
  return __builtin_bit_cast(short, h);
}
static __device__ __forceinline__ float bflo(unsigned int u) {
  return __builtin_bit_cast(float, u << 16);
}
static __device__ __forceinline__ float bfhi(unsigned int u) {
  return __builtin_bit_cast(float, u & 0xFFFF0000u);
}
static __device__ __forceinline__ unsigned int pk(float lo, float hi) {
  return (unsigned int)(unsigned short)f2bf(lo) |
         ((unsigned int)(unsigned short)f2bf(hi) << 16);
}
static __device__ __forceinline__ void glds16(const void* g, void* l) {
  __builtin_amdgcn_global_load_lds(
      (const __attribute__((address_space(1))) unsigned int*)g,
      (__attribute__((address_space(3))) unsigned int*)l, 16, 0, 0);
}

// per-block edge-dtype detection: int64 => odd 32-bit words of first 1024 pairs all zero
static __device__ __forceinline__ bool detect32(const int* __restrict__ ei, int* sm) {
  if (threadIdx.x == 0) *sm = 0;
  __syncthreads();
  int i = threadIdx.x & 255;
  int acc = ei[2 * i + 1] | ei[2 * (i + 256) + 1] |
            ei[2 * (i + 512) + 1] | ei[2 * (i + 768) + 1];
  if (acc != 0) atomicOr(sm, 1);
  __syncthreads();
  return *sm != 0;
}

// ---- phase 1: bucket edges by dst range into fixed-capacity regions ----
__global__ __launch_bounds__(256) void bucket_k(const int* __restrict__ ei,
                                                int* __restrict__ gcur,
                                                uint2* __restrict__ pairbuf) {
  __shared__ int sm;
  __shared__ int lcnt[NBUK], gpos[NBUK], loff[NBUK];
  bool is32 = detect32(ei, &sm);
  int t = threadIdx.x;
  int e0 = blockIdx.x * 4096;
  if (t < NBUK) lcnt[t] = 0;
  __syncthreads();
  int s_[16], d_[16];
#pragma unroll
  for (int k = 0; k < 16; ++k) {
    int e = e0 + k * 256 + t;
    int s = -1, d = -1;
    if (e < NEDGES) {
      if (is32) { s = ei[e];     d = ei[NEDGES + e]; }
      else      { s = ei[2 * e]; d = ei[2 * NEDGES + 2 * e]; }
    }
    s_[k] = s; d_[k] = d;
    if (d >= 0) atomicAdd(&lcnt[d >> 9], 1);
  }
  __syncthreads();
  if (t < NBUK) { gpos[t] = atomicAdd(&gcur[t], lcnt[t]); loff[t] = 0; }
  __syncthreads();
#pragma unroll
  for (int k = 0; k < 16; ++k) {
    int d = d_[k];
    if (d >= 0) {
      int b = d >> 9;
      int pos = gpos[b] + atomicAdd(&loff[b], 1);
      if (pos < (b + 1) * CAP) {  // safety vs capacity overflow
        uint2 p; p.x = (unsigned)s_[k]; p.y = (unsigned)d;
        pairbuf[pos] = p;
      }
    }
  }
}

// ---- phase 2: per-bucket CSR finalize: count, scan, rs/dinv, LDS-cursor scatter ----
__global__ __launch_bounds__(1024) void csr_k(const uint2* __restrict__ pairbuf,
                                              const int* __restrict__ gcur,
                                              int* __restrict__ rs,
                                              float* __restrict__ dinv,
                                              int* __restrict__ csrc) {
  __shared__ int lcnt[512];   // counts, then reused as global-position cursors
  __shared__ int lscan[512];
  __shared__ int ssz[256];    // bucket-size scan for gbase
  int t = threadIdx.x, b = blockIdx.x;
  int nbase = b * 512;
  if (t < 256) ssz[t] = (t < NBUK) ? (gcur[t] - t * CAP) : 0;
  if (t < 512) lcnt[t] = 0;
  __syncthreads();
  // inclusive scan of 196 bucket sizes (uniform loop, guarded ops)
  for (int off = 1; off < 256; off <<= 1) {
    int v = 0;
    if (t < 256 && t >= off) v = ssz[t - off];
    __syncthreads();
    if (t < 256) ssz[t] += v;
    __syncthreads();
  }
  int nb = gcur[b] - b * CAP;
  int gbase = (b > 0) ? ssz[b - 1] : 0;
  const uint2* mybuf = pairbuf + (size_t)b * CAP;

  // count
  for (int i = t; i < nb; i += 1024)
    atomicAdd(&lcnt[mybuf[i].y & 511], 1);
  __syncthreads();

  // exclusive scan of 512 counts (uniform loop, guarded ops)
  int c0 = (t < 512) ? lcnt[t] : 0;
  if (t < 512) lscan[t] = c0;
  __syncthreads();
  for (int off = 1; off < 512; off <<= 1) {
    int v = 0;
    if (t < 512 && t >= off) v = lscan[t - off];
    __syncthreads();
    if (t < 512) lscan[t] += v;
    __syncthreads();
  }
  int node = nbase + t;
  int r0 = 0;
  if (t < 512) {
    r0 = gbase + lscan[t] - c0;
    if (node < NNODES) { rs[node] = r0; dinv[node] = rsqrtf((float)(c0 + 1)); }
  }
  if (b == NBUK - 1 && t == 0) rs[NNODES] = NEDGES;
  __syncthreads();           // all reads of lcnt-as-counts done
  if (t < 512) lcnt[t] = r0; // cursors
  __syncthreads();

  // scatter within this bucket's csrc window (single CU / single L2)
  for (int i = t; i < nb; i += 1024) {
    uint2 p = mybuf[i];
    int pos = atomicAdd(&lcnt[p.y & 511], 1);
    csrc[pos] = (int)p.x;
  }
}

// ---- weight transpose+convert (merged) + gcur init ----
__global__ __launch_bounds__(256) void wt_k(const float* __restrict__ W1, short* __restrict__ W1t,
                                            const float* __restrict__ W2, short* __restrict__ W2t,
                                            int* __restrict__ gcur) {
  if (blockIdx.x == 0 && threadIdx.x < NBUK) gcur[threadIdx.x] = threadIdx.x * CAP;
  int i = blockIdx.x * 256 + threadIdx.x;
  if (i < NFEAT * NHID) {
    int k = i >> 7, c = i & 127;
    W1t[(size_t)c * NFEAT + k] = f2bf(W1[i]);
  } else {
    int j = i - NFEAT * NHID;
    if (j < NHID * NCLS) {
      int k = j >> 6, c = j & 63;
      W2t[(size_t)c * NHID + k] = f2bf(W2[j]);
    }
  }
}

// ---- fused MLP: BM=128, BK=64, 512 threads (8 waves), dbuf LDS A+B ----
__global__ __launch_bounds__(512, 4) void mlp3_k(const float* __restrict__ x,
                                                 const short* __restrict__ W1t,
                                                 const float* __restrict__ b1,
                                                 const short* __restrict__ W2t,
                                                 const float* __restrict__ b2,
                                                 const float* __restrict__ dinv,
                                                 unsigned short* __restrict__ x0,
                                                 unsigned short* __restrict__ g0) {
  __shared__ __align__(16) short As[2][8192]; // 2 x 128 rows x 64 k bf16
  __shared__ __align__(16) short Bs[2][8192]; // 2 x 128 col x 64 k bf16
  int tid = threadIdx.x, lane = tid & 63, wave = tid >> 6;
  int r = lane & 15, q = lane >> 4;
  int G = tid >> 4, li = tid & 15;        // A-staging: 32 row-groups x 16
  int row0 = blockIdx.x * 128;
  int wr = (wave >> 1) * 32, wc = (wave & 1) * 64;
  char* AsB = (char*)As;
  char* BsB = (char*)Bs;

  auto loadA = [&](float4* av, int kk) {
#pragma unroll
    for (int rd = 0; rd < 4; ++rd) {
      int row = rd * 32 + G;
      int grow = row0 + row; if (grow >= NNODES) grow = NNODES - 1;
      av[rd] = *reinterpret_cast<const float4*>(x + (size_t)grow * NFEAT + kk + li * 4);
    }
  };
  auto writeA = [&](const float4* av, int buf) {
#pragma unroll
    for (int rd = 0; rd < 4; ++rd) {
      int row = rd * 32 + G;
      uint2 u;
      u.x = pk(av[rd].x, av[rd].y);
      u.y = pk(av[rd].z, av[rd].w);
      *(uint2*)(AsB + buf * 16384 + row * 128 + (((li >> 1) ^ (row & 7)) << 4) + (li & 1) * 8) = u;
    }
  };
  auto stageB = [&](int buf, int kk) {
#pragma unroll
    for (int i2 = 0; i2 < 2; ++i2) {
      int i = wave * 2 + i2;
      int col = i * 8 + (lane >> 3);
      int srcg = (lane & 7) ^ (col & 7);
      glds16(W1t + (size_t)col * NFEAT + kk + srcg * 8, BsB + buf * 16384 + i * 1024);
    }
  };

  f4v acc[2][4];
#pragma unroll
  for (int a = 0; a < 2; ++a)
#pragma unroll
    for (int b = 0; b < 4; ++b) acc[a][b] = (f4v){0.f, 0.f, 0.f, 0.f};

  {
    float4 av[4];
    loadA(av, 0);
    stageB(0, 0);
    writeA(av, 0);
  }
  __syncthreads();

  int cur = 0;
  for (int c = 0; c < 8; ++c) {
    float4 av[4];
    if (c < 7) {               // issue next-tile loads early (T14)
      loadA(av, (c + 1) * 64);
      stageB(cur ^ 1, (c + 1) * 64);
    }
#pragma unroll
    for (int kc = 0; kc < 2; ++kc) {
      s8v af[2], bfr[4];
#pragma unroll
      for (int rt = 0; rt < 2; ++rt) {
        int arow = wr + rt * 16 + r;
        af[rt] = *(const s8v*)(AsB + cur * 16384 + arow * 128 +
                               (((kc * 4 + q) ^ (arow & 7)) << 4));
      }
#pragma unroll
      for (int ct = 0; ct < 4; ++ct) {
        int bcol = wc + ct * 16 + r;
        bfr[ct] = *(const s8v*)(BsB + cur * 16384 + bcol * 128 +
                                (((kc * 4 + q) ^ (bcol & 7)) << 4));
      }
#pragma unroll
      for (int rt = 0; rt < 2; ++rt)
#pragma unroll
        for (int ct = 0; ct < 4; ++ct)
          acc[rt][ct] = __builtin_amdgcn_mfma_f32_16x16x32_bf16(af[rt], bfr[ct], acc[rt][ct], 0, 0, 0);
    }
    if (c < 7) writeA(av, cur ^ 1);  // write-late
    __syncthreads();
    cur ^= 1;
  }

  // ---- h1 tile (relu, bf16) -> LDS (256B swizzled rows over As) ----
  {
    float bias1[4];
#pragma unroll
    for (int ct = 0; ct < 4; ++ct) bias1[ct] = b1[wc + ct * 16 + r];
#pragma unroll
    for (int rt = 0; rt < 2; ++rt)
#pragma unroll
      for (int ct = 0; ct < 4; ++ct) {
        int col = wc + ct * 16 + r;
#pragma unroll
        for (int j = 0; j < 4; ++j) {
          int row = wr + rt * 16 + q * 4 + j;
          float v = acc[rt][ct][j] + bias1[ct];
          v = v > 0.f ? v : 0.f;
          *(short*)(AsB + row * 256 + (((col >> 3) ^ (row & 15)) << 4) + (col & 7) * 2) = f2bf(v);
        }
      }
  }
  __syncthreads();

  // ---- gemm2: h1[128x128] @ W2t; wave: 32 rows x 32 cols ----
  int wc2 = (wave & 1) * 32;
  f4v acc2[2][2];
#pragma unroll
  for (int a = 0; a < 2; ++a)
#pragma unroll
    for (int b = 0; b < 2; ++b) acc2[a][b] = (f4v){0.f, 0.f, 0.f, 0.f};
#pragma unroll
  for (int kc = 0; kc < 4; ++kc) {
    s8v a2[2], b2f[2];
#pragma unroll
    for (int rt = 0; rt < 2; ++rt) {
      int row = wr + rt * 16 + r;
      a2[rt] = *(const s8v*)(AsB + row * 256 + (((kc * 4 + q) ^ (row & 15)) << 4));
    }
#pragma unroll
    for (int ct = 0; ct < 2; ++ct) {
      int col2 = wc2 + ct * 16 + r;
      b2f[ct] = *(const s8v*)(W2t + (size_t)col2 * NHID + kc * 32 + q * 8);
    }
#pragma unroll
    for (int rt = 0; rt < 2; ++rt)
#pragma unroll
      for (int ct = 0; ct < 2; ++ct)
        acc2[rt][ct] = __builtin_amdgcn_mfma_f32_16x16x32_bf16(a2[rt], b2f[ct], acc2[rt][ct], 0, 0, 0);
  }

  // ---- epilogue: pack x0/g0 into Bs (swizzled 128B rows), coalesced stores ----
  {
    float bias2[2];
#pragma unroll
    for (int ct = 0; ct < 2; ++ct) bias2[ct] = b2[wc2 + ct * 16 + r];
#pragma unroll
    for (int rt = 0; rt < 2; ++rt)
#pragma unroll
      for (int j = 0; j < 4; ++j) {
        int row = wr + rt * 16 + q * 4 + j;
        int grow = row0 + row;
        float dv = dinv[grow < NNODES ? grow : NNODES - 1];
#pragma unroll
        for (int ct = 0; ct < 2; ++ct) {
          float hh = acc2[rt][ct][j] + bias2[ct];
          int col = wc2 + ct * 16 + r;
          int byte = row * 128 + (((col >> 3) ^ (row & 7)) << 4) + (col & 7) * 2;
          *(short*)(BsB + byte) = f2bf(hh);
          *(short*)(BsB + 16384 + byte) = f2bf(dv * hh);
        }
      }
  }
  __syncthreads();
#pragma unroll
  for (int rd = 0; rd < 4; ++rd) {
    int row = rd * 32 + G;
    int grow = row0 + row;
    if (grow < NNODES) {
      int byte = row * 128 + (((li >> 1) ^ (row & 7)) << 4) + (li & 1) * 8;
      uint2 vx = *(const uint2*)(BsB + byte);
      uint2 vg = *(const uint2*)(BsB + 16384 + byte);
      *(uint2*)(x0 + (size_t)grow * NCLS + li * 4) = vx;
      *(uint2*)(g0 + (size_t)grow * NCLS + li * 4) = vg;
    }
  }
}

// ---- propagation: 8 nodes/wave, 8 lanes/node, uint4 gathers, pipelined csrc ----
__global__ __launch_bounds__(256) void prop_k(const unsigned short* __restrict__ gin,
                                              const unsigned short* __restrict__ x0,
                                              const float* __restrict__ dinv,
                                              const int* __restrict__ rs,
                                              const int* __restrict__ csrc,
                                              unsigned short* __restrict__ gout,
                                              float* __restrict__ out,
                                              int last) {
  int tid = threadIdx.x;
  int lane = tid & 63;
  int r = lane & 7;        // 8 lanes per node
  int gbase = lane & 56;
  int node = blockIdx.x * 32 + (tid >> 6) * 8 + (lane >> 3); // 3125*32 == NNODES
  int b = rs[node];
  int deg = rs[node + 1] - b;

  // hoisted loop-invariant loads (issue early)
  uint4 sv = ((const uint4*)(gin + (size_t)node * NCLS))[r];
  uint4 xv = ((const uint4*)(x0 + (size_t)node * NCLS))[r];
  float dvn = dinv[node];

  float a0 = bflo(sv.x), a1 = bfhi(sv.x), a2 = bflo(sv.y), a3 = bfhi(sv.y);
  float a4 = bflo(sv.z), a5 = bfhi(sv.z), a6 = bflo(sv.w), a7 = bfhi(sv.w);

  int m = deg;  // wave-uniform max
  m = max(m, __shfl_xor(m, 8));
  m = max(m, __shfl_xor(m, 16));
  m = max(m, __shfl_xor(m, 32));

  // software-pipelined index chunks: prefetch chunk k+1 while gathering chunk k
  int idx = NNODES;                       // null row (zeroed)
  if (r < deg) idx = csrc[b + r];
  for (int basek = 0; basek < m; basek += 8) {
    int nidx = NNODES;
    if (basek + 8 + r < deg) nidx = csrc[b + basek + 8 + r];
#pragma unroll
    for (int j = 0; j < 8; ++j) {
      int sj = __shfl(idx, gbase + j);
      uint4 v = ((const uint4*)(gin + (size_t)sj * NCLS))[r];
      a0 += bflo(v.x); a1 += bfhi(v.x); a2 += bflo(v.y); a3 += bfhi(v.y);
      a4 += bflo(v.z); a5 += bfhi(v.z); a6 += bflo(v.w); a7 += bfhi(v.w);
    }
    idx = nidx;
  }

  float h0 = 0.9f * (dvn * a0) + 0.1f * bflo(xv.x);
  float h1 = 0.9f * (dvn * a1) + 0.1f * bfhi(xv.x);
  float h2 = 0.9f * (dvn * a2) + 0.1f * bflo(xv.y);
  float h3 = 0.9f * (dvn * a3) + 0.1f * bfhi(xv.y);
  float h4 = 0.9f * (dvn * a4) + 0.1f * bflo(xv.z);
  float h5 = 0.9f * (dvn * a5) + 0.1f * bfhi(xv.z);
  float h6 = 0.9f * (dvn * a6) + 0.1f * bflo(xv.w);
  float h7 = 0.9f * (dvn * a7) + 0.1f * bfhi(xv.w);

  if (!last) {
    uint4 o;
    o.x = pk(dvn * h0, dvn * h1);
    o.y = pk(dvn * h2, dvn * h3);
    o.z = pk(dvn * h4, dvn * h5);
    o.w = pk(dvn * h6, dvn * h7);
    ((uint4*)(gout + (size_t)node * NCLS))[r] = o;
  } else {
    float mx = fmaxf(fmaxf(fmaxf(h0, h1), fmaxf(h2, h3)),
                     fmaxf(fmaxf(h4, h5), fmaxf(h6, h7)));
#pragma unroll
    for (int off = 1; off < 8; off <<= 1) mx = fmaxf(mx, __shfl_xor(mx, off));
    float s = __expf(h0 - mx) + __expf(h1 - mx) + __expf(h2 - mx) + __expf(h3 - mx) +
              __expf(h4 - mx) + __expf(h5 - mx) + __expf(h6 - mx) + __expf(h7 - mx);
#pragma unroll
    for (int off = 1; off < 8; off <<= 1) s += __shfl_xor(s, off);
    float ls = __logf(s);
    float* op = out + (size_t)node * NCLS + r * 8;
    float4 o0 = {h0 - mx - ls, h1 - mx - ls, h2 - mx - ls, h3 - mx - ls};
    float4 o1 = {h4 - mx - ls, h5 - mx - ls, h6 - mx - ls, h7 - mx - ls};
    *(float4*)(op) = o0;
    *(float4*)(op + 4) = o1;
  }
}

extern "C" void kernel_launch(void* const* d_in, const int* in_sizes, int n_in,
                              void* d_out, int out_size, void* d_ws, size_t ws_size,
                              hipStream_t stream) {
  const float* x  = (const float*)d_in[0];
  const int*   ei = (const int*)d_in[1];
  const float* W1 = (const float*)d_in[2];
  const float* b1 = (const float*)d_in[3];
  const float* W2 = (const float*)d_in[4];
  const float* b2 = (const float*)d_in[5];

  char* ws = (char*)d_ws;
  unsigned short* x0bf   = (unsigned short*)(ws);             // 12.8 MB (after CSR build)
  uint2*          pairbuf= (uint2*)(ws);                      // 14.45 MB, pre-mlp3 only
  unsigned short* gA     = (unsigned short*)(ws + 12800000);  // 12.8 MB + null row
  unsigned short* gB     = (unsigned short*)(ws + 25600256);  // 12.8 MB + null row
  int*            csrc   = (int*)(ws + 38400384);             // 6.4 MB
  int*            rs     = (int*)(ws + 45200384);             // 400.128 KB
  float*          dinv   = (float*)(ws + 46000512);           // 400 KB
  short*          W1t    = (short*)(ws + 46800512);           // 128 KB
  short*          W2t    = (short*)(ws + 46931584);           // 16 KB
  int*            gcur   = (int*)(ws + 46950144);             // 196 ints

  // zero null-gather row (index NNODES) in both state buffers
  hipMemsetAsync((char*)gA + (size_t)NNODES * NCLS * 2, 0, 128, stream);
  hipMemsetAsync((char*)gB + (size_t)NNODES * NCLS * 2, 0, 128, stream);

  wt_k<<<(NFEAT * NHID + NHID * NCLS + 255) / 256, 256, 0, stream>>>(W1, W1t, W2, W2t, gcur);
  bucket_k<<<(NEDGES + 4095) / 4096, 256, 0, stream>>>(ei, gcur, pairbuf);
  csr_k<<<NBUK, 1024, 0, stream>>>(pairbuf, gcur, rs, dinv, csrc);

  mlp3_k<<<(NNODES + 127) / 128, 512, 0, stream>>>(x, W1t, b1, W2t, b2, dinv, x0bf, gB);

  // g0 in gB; odd t writes gA, even t writes gB; t=10 reads gA, writes d_out (f32)
  for (int t = 1; t <= 10; ++t) {
    const unsigned short* gin = (t & 1) ? gB : gA;
    unsigned short* gout      = (t & 1) ? gA : gB;
    prop_k<<<NNODES / 32, 256, 0, stream>>>(gin, x0bf, dinv, rs, csrc, gout,
                                            (float*)d_out, t == 10);
  }
}